// Round 11
// baseline (294.579 us; speedup 1.0000x reference)
//
#include <hip/hip_runtime.h>
#include <hip/hip_bf16.h>
#include <stdint.h>

#define B_ROWS 32768
#define DIM    1024
#define KACT   102       // int(1024*0.1)
#define KPAD   104

typedef short bf16x8 __attribute__((ext_vector_type(8)));
typedef unsigned short u16x8 __attribute__((ext_vector_type(8)));
typedef float f32x4  __attribute__((ext_vector_type(4)));

__device__ __forceinline__ unsigned short f2bf(float f) {
  union { float f; unsigned u; } v; v.f = f;
  unsigned u = v.u;
  unsigned r = u + 0x7fffu + ((u >> 16) & 1u);   // RNE
  return (unsigned short)(r >> 16);
}
__device__ __forceinline__ float bfasf(unsigned hi16) {   // f32 from top-16 bits
  union { unsigned u; float f; } v; v.u = hi16;
  return v.f;
}

// async global->LDS, 16B per lane
#define GLDS(g, l) __builtin_amdgcn_global_load_lds( \
    (__attribute__((address_space(1))) void*)(g),    \
    (__attribute__((address_space(3))) void*)(l), 16, 0, 0)

// ---------------------------------------------------------------------------
// K1: merged conv + w1t (R7 verbatim) + zero the aux ticket counter.
// ---------------------------------------------------------------------------
__global__ __launch_bounds__(256) void k_convw(
    const float* __restrict__ x, const float* __restrict__ w1,
    unsigned short* __restrict__ xb, unsigned short* __restrict__ w1t,
    float* __restrict__ partial, int* __restrict__ ctr) {
  const int t = threadIdx.x;
  if (blockIdx.x == 0 && t == 0) *ctr = 0;   // reset ticket each call
  if (blockIdx.x < 512) {
    const int c0 = t * 4;
    const size_t base = (size_t)blockIdx.x * 64 * DIM;
    float s0 = 0.f, s1 = 0.f, s2 = 0.f, s3 = 0.f;
    #pragma unroll 4
    for (int j = 0; j < 64; ++j) {
      size_t off = base + (size_t)j * DIM + c0;
      float4 v = *(const float4*)(x + off);
      s0 += fabsf(v.x); s1 += fabsf(v.y); s2 += fabsf(v.z); s3 += fabsf(v.w);
      ushort4 o;
      o.x = f2bf(v.x); o.y = f2bf(v.y); o.z = f2bf(v.z); o.w = f2bf(v.w);
      *(ushort4*)(xb + off) = o;
    }
    float4 p; p.x = s0; p.y = s1; p.z = s2; p.w = s3;
    *(float4*)(partial + (size_t)blockIdx.x * DIM + c0) = p;
  } else {
    __shared__ unsigned short tile[64][65];
    const int b  = blockIdx.x - 512;
    const int bx = b & 15;
    const int by = b >> 4;
    for (int e = t; e < 64 * 64; e += 256) {
      int r = e >> 6, c = e & 63;
      tile[r][c] = f2bf(w1[(size_t)(by * 64 + r) * DIM + bx * 64 + c]);
    }
    __syncthreads();
    for (int e = t; e < 64 * 64; e += 256) {
      int c = e >> 6, r = e & 63;
      w1t[(size_t)(bx * 64 + c) * DIM + by * 64 + r] = tile[r][c];
    }
  }
}

// ---------------------------------------------------------------------------
// K5: COMBINED gemm (blocks 0..511, R10 verbatim incl. depth-3 pipeline) +
// aux chain (blocks 512..527): reduce partial->p2, last-finisher ticket ->
// rank+compact+wsub. Aux work (~3 MB traffic) hides under the ~70 us GEMM.
// ---------------------------------------------------------------------------
#define VMW8 asm volatile("s_waitcnt vmcnt(8)" ::: "memory")
#define VMW4 asm volatile("s_waitcnt vmcnt(4)" ::: "memory")
#define VMW0 asm volatile("s_waitcnt vmcnt(0)" ::: "memory")
#define NOP_ (void)0

#define STAGE_A(KT) do { \
  GLDS(Abase + (size_t)sr0 * 1024 + (KT) * 32 + sc0 * 8, &Asl[((KT)&3)*8192 + p0*8]); \
  GLDS(Abase + (size_t)sr1 * 1024 + (KT) * 32 + sc1 * 8, &Asl[((KT)&3)*8192 + p1*8]); \
} while (0)
#define STAGE_B(KT) do { \
  GLDS(Bbase + (size_t)sr0 * 1024 + (KT) * 32 + sc0 * 8, &Bsl[((KT)&3)*8192 + p0*8]); \
  GLDS(Bbase + (size_t)sr1 * 1024 + (KT) * 32 + sc1 * 8, &Bsl[((KT)&3)*8192 + p1*8]); \
} while (0)

#define PH0(SLOT, STAGE_STMT) do { \
  _Pragma("unroll") for (int i = 0; i < 4; ++i) \
    areg[i] = *(const bf16x8*)(&Asl[(SLOT)*8192 + aoff0 + i * 512]); \
  _Pragma("unroll") for (int i = 0; i < 4; ++i) \
    breg[i] = *(const bf16x8*)(&Bsl[(SLOT)*8192 + boff0 + i * 512]); \
  STAGE_STMT; \
  __builtin_amdgcn_s_barrier(); \
  __builtin_amdgcn_s_setprio(1); \
  _Pragma("unroll") for (int mi = 0; mi < 4; ++mi) \
  _Pragma("unroll") for (int ni = 0; ni < 4; ++ni) \
    acc[mi][ni] = __builtin_amdgcn_mfma_f32_16x16x32_bf16(areg[mi], breg[ni], acc[mi][ni], 0, 0, 0); \
  __builtin_amdgcn_s_setprio(0); \
  __builtin_amdgcn_s_barrier(); \
} while (0)

#define PH1(SLOT, STAGE_STMT, WAIT_STMT) do { \
  _Pragma("unroll") for (int i = 0; i < 4; ++i) \
    areg[i] = *(const bf16x8*)(&Asl[(SLOT)*8192 + aoff0 + 2048 + i * 512]); \
  STAGE_STMT; \
  WAIT_STMT; \
  __builtin_amdgcn_s_barrier(); \
  __builtin_amdgcn_s_setprio(1); \
  _Pragma("unroll") for (int mi = 0; mi < 4; ++mi) \
  _Pragma("unroll") for (int ni = 0; ni < 4; ++ni) \
    acc[4 + mi][ni] = __builtin_amdgcn_mfma_f32_16x16x32_bf16(areg[mi], breg[ni], acc[4 + mi][ni], 0, 0, 0); \
  __builtin_amdgcn_s_setprio(0); \
  __builtin_amdgcn_s_barrier(); \
} while (0)

__global__ __launch_bounds__(512, 1) void k_gemm_aux(
    const unsigned short* __restrict__ A,
    const unsigned short* __restrict__ Bt,
    float* __restrict__ C,
    const float* __restrict__ partial,
    float* __restrict__ p2,
    const float* __restrict__ w2,
    const float* __restrict__ w3,
    int* __restrict__ ctr,
    int* __restrict__ cmap,
    float* __restrict__ W2sub,
    float* __restrict__ W3sub) {
  __shared__ __align__(16) char smem[131072];
  const int t = threadIdx.x;

  if (blockIdx.x < 512) {
    // ------------------------- GEMM role (R10 verbatim) -------------------
    unsigned short* Asl = (unsigned short*)smem;
    unsigned short* Bsl = (unsigned short*)(smem + 65536);

    const int lane = t & 63;
    const int wave = t >> 6;
    const int wm   = wave >> 2;
    const int wn   = wave & 3;
    const int la   = lane & 15;
    const int kg   = lane >> 4;
    const int kgx  = kg ^ ((la >> 1) & 3);

    const int swz  = (blockIdx.x & 7) * 64 + (blockIdx.x >> 3);
    const int brow = swz >> 2;
    const int bcol = swz & 3;

    const unsigned short* Abase = A  + (size_t)brow * 256 * 1024;
    const unsigned short* Bbase = Bt + (size_t)bcol * 256 * 1024;

    const int p0 = t, p1 = t + 512;
    const int q0 = p0 ^ ((p0 >> 3) & 3);
    const int q1 = p1 ^ ((p1 >> 3) & 3);
    const int sr0 = q0 >> 2, sc0 = q0 & 3;
    const int sr1 = q1 >> 2, sc1 = q1 & 3;

    const int aoff0 = (wm * 128 + la) * 32 + kgx * 8;
    const int boff0 = (wn * 64  + la) * 32 + kgx * 8;

    f32x4 acc[8][4];
    #pragma unroll
    for (int mi = 0; mi < 8; ++mi)
      #pragma unroll
      for (int ni = 0; ni < 4; ++ni)
        acc[mi][ni] = (f32x4){0.f, 0.f, 0.f, 0.f};

    bf16x8 areg[4], breg[4];

    STAGE_A(0); STAGE_B(0); STAGE_A(1); STAGE_B(1); STAGE_A(2); STAGE_B(2);
    VMW8;
    __builtin_amdgcn_s_barrier();

    for (int kt4 = 0; kt4 < 28; kt4 += 4) {
      PH0(0, STAGE_A(kt4 + 3)); PH1(0, STAGE_B(kt4 + 3), VMW8);
      PH0(1, STAGE_A(kt4 + 4)); PH1(1, STAGE_B(kt4 + 4), VMW8);
      PH0(2, STAGE_A(kt4 + 5)); PH1(2, STAGE_B(kt4 + 5), VMW8);
      PH0(3, STAGE_A(kt4 + 6)); PH1(3, STAGE_B(kt4 + 6), VMW8);
    }
    PH0(0, STAGE_A(31)); PH1(0, STAGE_B(31), VMW8);
    PH0(1, NOP_);        PH1(1, NOP_, VMW4);
    PH0(2, NOP_);        PH1(2, NOP_, VMW0);
    PH0(3, NOP_);        PH1(3, NOP_, NOP_);

    const int orow0 = brow * 256 + wm * 128 + (lane >> 4) * 4;
    const int ocol0 = bcol * 256 + wn * 64 + la;
    #pragma unroll
    for (int mi = 0; mi < 8; ++mi)
      #pragma unroll
      for (int ni = 0; ni < 4; ++ni)
        #pragma unroll
        for (int r = 0; r < 4; ++r)
          C[(size_t)(orow0 + mi * 16 + r) * DIM + ocol0 + ni * 16] = acc[mi][ni][r];
  } else {
    // ------------------------- aux role -----------------------------------
    // phase 1: reduce partial -> p2. 16 blocks x 512 thr = 8192 (ks,c) pairs.
    const int a    = blockIdx.x - 512;          // 0..15
    const int pair = a * 512 + t;               // 0..8191
    const int ks   = pair >> 10;
    const int c    = pair & 1023;
    {
      float s = 0.f;
      #pragma unroll 8
      for (int p = ks * 64; p < ks * 64 + 64; ++p) s += partial[(size_t)p * DIM + c];
      p2[ks * DIM + c] = s;
    }
    __threadfence();
    __syncthreads();
    __shared__ int lastFlag;
    if (t == 0) lastFlag = (atomicAdd(ctr, 1) == 15);
    __syncthreads();
    if (!lastFlag) return;
    __threadfence();

    // phase 2 (last block only): rank + compact + wsub.
    // Rank arithmetic identical to prior passing k_sel (f64 sum of 8 f32
    // slices, ks order 0..7; tie-break lower index == lax.top_k).
    double* sv  = (double*)smem;                 // 8192 B
    int*    af  = (int*)(smem + 8192);           // 4096 B
    int*    acts= (int*)(smem + 12288);          // KACT ints
    #pragma unroll
    for (int h = 0; h < 2; ++h) {
      int d = t + h * 512;
      double s = 0.0;
      #pragma unroll
      for (int k8 = 0; k8 < 8; ++k8) s += (double)p2[k8 * DIM + d];
      sv[d] = s;
    }
    __syncthreads();
    #pragma unroll
    for (int h = 0; h < 2; ++h) {
      int d = t + h * 512;
      const double sd = sv[d];
      int rank = 0;
      for (int j = 0; j < DIM; ++j) {
        double s = sv[j];
        rank += (s > sd || (s == sd && j < d)) ? 1 : 0;
      }
      af[d] = (rank < KACT) ? 1 : 0;
    }
    __syncthreads();
    #pragma unroll
    for (int h = 0; h < 2; ++h) {
      int d = t + h * 512;
      int f = af[d];
      int pos = 0;
      for (int j = 0; j < d; ++j) pos += af[j];
      cmap[d] = f ? pos : -1;
      if (f) acts[pos] = d;
    }
    __syncthreads();
    for (int e = t; e < KPAD * KPAD; e += 512) {
      int i = e / KPAD, j = e - i * KPAD;
      float v2 = 0.f, v3 = 0.f;
      if (i < KACT && j < KACT) {
        size_t o = (size_t)acts[i] * DIM + acts[j];
        v2 = w2[o]; v3 = w3[o];
      }
      W2sub[e] = v2; W3sub[e] = v3;
    }
  }
}

// ---------------------------------------------------------------------------
// K6: r2/r3 — R7/R10 verbatim.
// ---------------------------------------------------------------------------
__global__ __launch_bounds__(512) void k_r23(
    const unsigned short* __restrict__ xb,
    const float* __restrict__ W2sub,
    const float* __restrict__ W3sub,
    const int* __restrict__ cmap,
    float* __restrict__ out2,
    float* __restrict__ out3) {
  __shared__ float W2s[KPAD * KPAD];
  __shared__ float W3s[KPAD * KPAD];
  __shared__ float xs[2][16 * KPAD];
  __shared__ float r2s[16 * KPAD];
  __shared__ float r3s[16 * KPAD];
  __shared__ int   cms[DIM];
  const int t    = threadIdx.x;
  const int row0 = blockIdx.x * 128;

  for (int e = t; e < KPAD * KPAD; e += 512) { W2s[e] = W2sub[e]; W3s[e] = W3sub[e]; }
  for (int e = t; e < DIM; e += 512) cms[e] = cmap[e];
  for (int e = t; e < 2 * 16 * KPAD; e += 512) ((float*)xs)[e] = 0.f;
  __syncthreads();

  const int  j   = t & 127;
  const int  rg  = (t >> 7) & 3;
  const bool jok = j < KACT;

  auto LOADR = [&](int ch, u16x8* ld) {
    const size_t base = (size_t)(row0 + ch * 16) * DIM;
    #pragma unroll
    for (int it = 0; it < 4; ++it) {
      int e = t + it * 512;
      int r = e >> 7, c8 = e & 127;
      ld[it] = *(const u16x8*)(xb + base + (size_t)r * DIM + c8 * 8);
    }
  };
  auto XSW = [&](int buf, const u16x8* ld) {
    #pragma unroll
    for (int it = 0; it < 4; ++it) {
      int e = t + it * 512;
      int r = e >> 7, c8 = e & 127;
      #pragma unroll
      for (int q = 0; q < 8; ++q) {
        int m = cms[c8 * 8 + q];
        if (m >= 0) xs[buf][r * KPAD + m] = bfasf(((unsigned)(unsigned short)ld[it][q]) << 16);
      }
    }
  };
  auto COMPUTE = [&](int buf) {
    if (jok) {
      float a2[4], a3[4];
      #pragma unroll
      for (int r = 0; r < 4; ++r) { a2[r] = 0.f; a3[r] = 0.f; }
      for (int i = 0; i < KPAD; i += 4) {
        float w2v[4], w3v[4];
        #pragma unroll
        for (int q = 0; q < 4; ++q) {
          w2v[q] = W2s[(i + q) * KPAD + j];
          w3v[q] = W3s[(i + q) * KPAD + j];
        }
        #pragma unroll
        for (int r = 0; r < 4; ++r) {
          f32x4 xv = *(const f32x4*)(&xs[buf][(rg * 4 + r) * KPAD + i]);
          a2[r] += xv[0] * w2v[0] + xv[1] * w2v[1] + xv[2] * w2v[2] + xv[3] * w2v[3];
          a3[r] += xv[0] * w3v[0] + xv[1] * w3v[1] + xv[2] * w3v[2] + xv[3] * w3v[3];
        }
      }
      #pragma unroll
      for (int r = 0; r < 4; ++r) {
        int rr = rg * 4 + r;
        float g = xs[buf][rr * KPAD + j];
        r2s[rr * KPAD + j] = a2[r] * g;
        r3s[rr * KPAD + j] = a3[r] * a3[r] * g;
      }
    }
  };
  auto WRITEOUT = [&](int ch) {
    const int r0 = row0 + ch * 16;
    const int c0 = (t & 255) * 4;
    const int rh = t >> 8;
    const int4 cm = *(const int4*)(&cms[c0]);
    #pragma unroll
    for (int k = 0; k < 8; ++k) {
      int r = rh + k * 2;
      const float* rr2 = &r2s[r * KPAD];
      const float* rr3 = &r3s[r * KPAD];
      float4 o2, o3;
      o2.x = (cm.x >= 0) ? rr2[cm.x] : 0.f;  o3.x = (cm.x >= 0) ? rr3[cm.x] : 0.f;
      o2.y = (cm.y >= 0) ? rr2[cm.y] : 0.f;  o3.y = (cm.y >= 0) ? rr3[cm.y] : 0.f;
      o2.z = (cm.z >= 0) ? rr2[cm.z] : 0.f;  o3.z = (cm.z >= 0) ? rr3[cm.z] : 0.f;
      o2.w = (cm.w >= 0) ? rr2[cm.w] : 0.f;  o3.w = (cm.w >= 0) ? rr3[cm.w] : 0.f;
      size_t oo = (size_t)(r0 + r) * DIM + c0;
      *(float4*)(out2 + oo) = o2;
      *(float4*)(out3 + oo) = o3;
    }
  };

  u16x8 ldA[4], ldB[4];
  LOADR(0, ldA);
  XSW(0, ldA);
  __syncthreads();
  for (int ch2 = 0; ch2 < 8; ch2 += 2) {
    if (ch2 + 1 < 8) LOADR(ch2 + 1, ldB);
    COMPUTE(0);
    __syncthreads();
    WRITEOUT(ch2);
    if (ch2 + 1 < 8) XSW(1, ldB);
    __syncthreads();
    if (ch2 + 2 < 8) LOADR(ch2 + 2, ldA);
    COMPUTE(1);
    __syncthreads();
    WRITEOUT(ch2 + 1);
    if (ch2 + 2 < 8) XSW(0, ldA);
    __syncthreads();
  }
}

// ---------------------------------------------------------------------------
extern "C" void kernel_launch(void* const* d_in, const int* in_sizes, int n_in,
                              void* d_out, int out_size, void* d_ws, size_t ws_size,
                              hipStream_t stream) {
  const float* x  = (const float*)d_in[0];
  const float* w1 = (const float*)d_in[1];
  const float* w2 = (const float*)d_in[2];
  const float* w3 = (const float*)d_in[3];

  float* out1 = (float*)d_out;
  float* out2 = out1 + (size_t)B_ROWS * DIM;
  float* out3 = out2 + (size_t)B_ROWS * DIM;

  char* ws = (char*)d_ws;
  unsigned short* xb     = (unsigned short*)ws;                  // 67108864 B
  unsigned short* w1t    = (unsigned short*)(ws + 67108864);     //  2097152 B
  float*          partial= (float*)(ws + 69206016);              //  2097152 B
  float*          p2     = (float*)(ws + 71303168);              //    32768 B
  int*            cmap   = (int*)(ws + 71335936);                //     4096 B
  int*            ctr    = (int*)(ws + 71340032);                //      512 B
  float*          W2sub  = (float*)(ws + 71340544);              //    43264 B
  float*          W3sub  = (float*)(ws + 71383808);              //    43264 B

  k_convw    <<<dim3(768), dim3(256), 0, stream>>>(x, w1, xb, w1t, partial, ctr);
  k_gemm_aux <<<dim3(528), dim3(512), 0, stream>>>(xb, w1t, out1, partial, p2,
                                                   w2, w3, ctr, cmap, W2sub, W3sub);
  k_r23      <<<dim3(256), dim3(512), 0, stream>>>(xb, W2sub, W3sub, cmap, out2, out3);
}

// Round 15
// 257.925 us; speedup vs baseline: 1.1421x; 1.1421x over previous
//
#include <hip/hip_runtime.h>
#include <hip/hip_bf16.h>
#include <stdint.h>

#define B_ROWS 32768
#define DIM    1024
#define KACT   102       // int(1024*0.1)
#define KPAD   104

typedef short bf16x8 __attribute__((ext_vector_type(8)));
typedef unsigned short u16x8 __attribute__((ext_vector_type(8)));
typedef float f32x4  __attribute__((ext_vector_type(4)));

__device__ __forceinline__ unsigned short f2bf(float f) {
  union { float f; unsigned u; } v; v.f = f;
  unsigned u = v.u;
  unsigned r = u + 0x7fffu + ((u >> 16) & 1u);   // RNE
  return (unsigned short)(r >> 16);
}
__device__ __forceinline__ float bfasf(unsigned hi16) {   // f32 from top-16 bits
  union { unsigned u; float f; } v; v.u = hi16;
  return v.f;
}

// async global->LDS, 16B per lane
#define GLDS(g, l) __builtin_amdgcn_global_load_lds( \
    (__attribute__((address_space(1))) void*)(g),    \
    (__attribute__((address_space(3))) void*)(l), 16, 0, 0)

// ---------------------------------------------------------------------------
// K1: merged conv + w1t (R10 verbatim).
// ---------------------------------------------------------------------------
__global__ __launch_bounds__(256) void k_convw(
    const float* __restrict__ x, const float* __restrict__ w1,
    unsigned short* __restrict__ xb, unsigned short* __restrict__ w1t,
    float* __restrict__ partial) {
  const int t = threadIdx.x;
  if (blockIdx.x < 512) {
    const int c0 = t * 4;
    const size_t base = (size_t)blockIdx.x * 64 * DIM;
    float s0 = 0.f, s1 = 0.f, s2 = 0.f, s3 = 0.f;
    #pragma unroll 4
    for (int j = 0; j < 64; ++j) {
      size_t off = base + (size_t)j * DIM + c0;
      float4 v = *(const float4*)(x + off);
      s0 += fabsf(v.x); s1 += fabsf(v.y); s2 += fabsf(v.z); s3 += fabsf(v.w);
      ushort4 o;
      o.x = f2bf(v.x); o.y = f2bf(v.y); o.z = f2bf(v.z); o.w = f2bf(v.w);
      *(ushort4*)(xb + off) = o;
    }
    float4 p; p.x = s0; p.y = s1; p.z = s2; p.w = s3;
    *(float4*)(partial + (size_t)blockIdx.x * DIM + c0) = p;
  } else {
    __shared__ unsigned short tile[64][65];
    const int b  = blockIdx.x - 512;
    const int bx = b & 15;
    const int by = b >> 4;
    for (int e = t; e < 64 * 64; e += 256) {
      int r = e >> 6, c = e & 63;
      tile[r][c] = f2bf(w1[(size_t)(by * 64 + r) * DIM + bx * 64 + c]);
    }
    __syncthreads();
    for (int e = t; e < 64 * 64; e += 256) {
      int c = e >> 6, r = e & 63;
      w1t[(size_t)(bx * 64 + c) * DIM + by * 64 + r] = tile[r][c];
    }
  }
}

// ---------------------------------------------------------------------------
// K2: reduce 512 partials -> 8 k-slice partials (R10 verbatim).
// ---------------------------------------------------------------------------
__global__ __launch_bounds__(128) void k_reduce1(const float* __restrict__ partial,
                                                 float* __restrict__ p2) {
  const int c  = (blockIdx.x & 7) * 128 + threadIdx.x;
  const int ks = blockIdx.x >> 3;
  float s = 0.f;
  #pragma unroll 8
  for (int p = ks * 64; p < ks * 64 + 64; ++p) s += partial[(size_t)p * DIM + c];
  p2[ks * DIM + c] = s;
}

// ---------------------------------------------------------------------------
// K3: rank + compact (R10 verbatim).
// ---------------------------------------------------------------------------
__global__ __launch_bounds__(1024) void k_sel(const float* __restrict__ p2,
                                              int* __restrict__ act,
                                              int* __restrict__ cmap) {
  __shared__ double sv[DIM];
  __shared__ int wcnt[16];
  const int d = threadIdx.x;
  {
    double s = 0.0;
    #pragma unroll
    for (int ks = 0; ks < 8; ++ks) s += (double)p2[ks * DIM + d];
    sv[d] = s;
  }
  __syncthreads();
  const double sd = sv[d];
  int rank = 0;
  for (int j = 0; j < DIM; ++j) {
    double s = sv[j];
    rank += (s > sd || (s == sd && j < d)) ? 1 : 0;
  }
  const int f = (rank < KACT) ? 1 : 0;
  unsigned long long m = __ballot(f != 0);
  const int lane = d & 63, w = d >> 6;
  if (lane == 0) wcnt[w] = __popcll(m);
  __syncthreads();
  int off = 0;
  for (int i = 0; i < w; ++i) off += wcnt[i];
  int pos = off + __popcll(m & ((1ull << lane) - 1ull));
  cmap[d] = f ? pos : -1;
  if (f) act[pos] = d;
}

// ---------------------------------------------------------------------------
// K4: gather compact W2sub/W3sub (R10 verbatim).
// ---------------------------------------------------------------------------
__global__ __launch_bounds__(128) void k_wsub(const float* __restrict__ w2,
                                              const float* __restrict__ w3,
                                              const int* __restrict__ act,
                                              float* __restrict__ W2sub,
                                              float* __restrict__ W3sub) {
  const int i = blockIdx.x;
  const int j = threadIdx.x;
  if (j >= KPAD) return;
  float v2 = 0.f, v3 = 0.f;
  if (i < KACT && j < KACT) {
    size_t o = (size_t)act[i] * DIM + act[j];
    v2 = w2[o]; v3 = w3[o];
  }
  W2sub[i * KPAD + j] = v2;
  W3sub[i * KPAD + j] = v3;
}

// ---------------------------------------------------------------------------
// K5: r1 = x @ w1 bf16 MFMA. R10 ring/vmcnt accounting; SINGLE CHANGE:
// merged phase per K-tile — 12 clustered ds_read_b128 + stage(kt+3) +
// vmcnt(8) + barrier + 32-MFMA setprio cluster + barrier. Barriers/block
// 128 -> 64. WAR-safe: staging kt+3 writes slot (kt-1)&3, whose reads
// completed before each wave's MFMA(kt-1), which precedes the post-barrier.
// ---------------------------------------------------------------------------
#define VMW8 asm volatile("s_waitcnt vmcnt(8)" ::: "memory")
#define VMW4 asm volatile("s_waitcnt vmcnt(4)" ::: "memory")
#define VMW0 asm volatile("s_waitcnt vmcnt(0)" ::: "memory")
#define NOP_ (void)0

#define STAGE_A(KT) do { \
  GLDS(Abase + (size_t)sr0 * 1024 + (KT) * 32 + sc0 * 8, &Asl[((KT)&3)*8192 + p0*8]); \
  GLDS(Abase + (size_t)sr1 * 1024 + (KT) * 32 + sc1 * 8, &Asl[((KT)&3)*8192 + p1*8]); \
} while (0)
#define STAGE_B(KT) do { \
  GLDS(Bbase + (size_t)sr0 * 1024 + (KT) * 32 + sc0 * 8, &Bsl[((KT)&3)*8192 + p0*8]); \
  GLDS(Bbase + (size_t)sr1 * 1024 + (KT) * 32 + sc1 * 8, &Bsl[((KT)&3)*8192 + p1*8]); \
} while (0)

#define KT(SLOT, STAGE_STMT, WAIT_STMT) do { \
  _Pragma("unroll") for (int i = 0; i < 8; ++i) \
    areg[i] = *(const bf16x8*)(&Asl[(SLOT)*8192 + aoff0 + i * 512]); \
  _Pragma("unroll") for (int i = 0; i < 4; ++i) \
    breg[i] = *(const bf16x8*)(&Bsl[(SLOT)*8192 + boff0 + i * 512]); \
  STAGE_STMT; \
  WAIT_STMT; \
  __builtin_amdgcn_s_barrier(); \
  __builtin_amdgcn_s_setprio(1); \
  _Pragma("unroll") for (int mi = 0; mi < 8; ++mi) \
  _Pragma("unroll") for (int ni = 0; ni < 4; ++ni) \
    acc[mi][ni] = __builtin_amdgcn_mfma_f32_16x16x32_bf16(areg[mi], breg[ni], acc[mi][ni], 0, 0, 0); \
  __builtin_amdgcn_s_setprio(0); \
  __builtin_amdgcn_s_barrier(); \
} while (0)

__global__ __launch_bounds__(512, 1) void k_gemm_r1(
    const unsigned short* __restrict__ A,
    const unsigned short* __restrict__ Bt,
    float* __restrict__ C) {
  __shared__ unsigned short Asl[4 * 8192];
  __shared__ unsigned short Bsl[4 * 8192];

  const int t    = threadIdx.x;
  const int lane = t & 63;
  const int wave = t >> 6;
  const int wm   = wave >> 2;
  const int wn   = wave & 3;
  const int la   = lane & 15;
  const int kg   = lane >> 4;
  const int kgx  = kg ^ ((la >> 1) & 3);

  const int swz  = (blockIdx.x & 7) * 64 + (blockIdx.x >> 3);
  const int brow = swz >> 2;
  const int bcol = swz & 3;

  const unsigned short* Abase = A  + (size_t)brow * 256 * 1024;
  const unsigned short* Bbase = Bt + (size_t)bcol * 256 * 1024;

  const int p0 = t, p1 = t + 512;
  const int q0 = p0 ^ ((p0 >> 3) & 3);
  const int q1 = p1 ^ ((p1 >> 3) & 3);
  const int sr0 = q0 >> 2, sc0 = q0 & 3;
  const int sr1 = q1 >> 2, sc1 = q1 & 3;

  const int aoff0 = (wm * 128 + la) * 32 + kgx * 8;
  const int boff0 = (wn * 64  + la) * 32 + kgx * 8;

  f32x4 acc[8][4];
  #pragma unroll
  for (int mi = 0; mi < 8; ++mi)
    #pragma unroll
    for (int ni = 0; ni < 4; ++ni)
      acc[mi][ni] = (f32x4){0.f, 0.f, 0.f, 0.f};

  bf16x8 areg[8], breg[4];

  // prologue: stage tiles 0,1,2 (12 loads); wait for tile 0 (8 in flight)
  STAGE_A(0); STAGE_B(0); STAGE_A(1); STAGE_B(1); STAGE_A(2); STAGE_B(2);
  VMW8;
  __builtin_amdgcn_s_barrier();

  // steady: compute kt, stage kt+3, vmcnt(8) -> tile kt+1 landed
  for (int kt4 = 0; kt4 < 28; kt4 += 4) {
    KT(0, STAGE_A(kt4 + 3); STAGE_B(kt4 + 3), VMW8);
    KT(1, STAGE_A(kt4 + 4); STAGE_B(kt4 + 4), VMW8);
    KT(2, STAGE_A(kt4 + 5); STAGE_B(kt4 + 5), VMW8);
    KT(3, STAGE_A(kt4 + 6); STAGE_B(kt4 + 6), VMW8);
  }
  KT(0, STAGE_A(31); STAGE_B(31), VMW8);   // kt=28 (last stage)
  KT(1, NOP_, VMW4);                        // kt=29 (tile 30 landed)
  KT(2, NOP_, VMW0);                        // kt=30 (tile 31 landed)
  KT(3, NOP_, NOP_);                        // kt=31

  // C/D layout: col = lane&15, row = (lane>>4)*4 + reg
  const int orow0 = brow * 256 + wm * 128 + (lane >> 4) * 4;
  const int ocol0 = bcol * 256 + wn * 64 + la;
  #pragma unroll
  for (int mi = 0; mi < 8; ++mi)
    #pragma unroll
    for (int ni = 0; ni < 4; ++ni)
      #pragma unroll
      for (int r = 0; r < 4; ++r)
        C[(size_t)(orow0 + mi * 16 + r) * DIM + ocol0 + ni * 16] = acc[mi][ni][r];
}

// ---------------------------------------------------------------------------
// K6: r2/r3 — R10 verbatim.
// ---------------------------------------------------------------------------
__global__ __launch_bounds__(512) void k_r23(
    const unsigned short* __restrict__ xb,
    const float* __restrict__ W2sub,
    const float* __restrict__ W3sub,
    const int* __restrict__ cmap,
    float* __restrict__ out2,
    float* __restrict__ out3) {
  __shared__ float W2s[KPAD * KPAD];
  __shared__ float W3s[KPAD * KPAD];
  __shared__ float xs[2][16 * KPAD];
  __shared__ float r2s[16 * KPAD];
  __shared__ float r3s[16 * KPAD];
  __shared__ int   cms[DIM];
  const int t    = threadIdx.x;
  const int row0 = blockIdx.x * 128;

  for (int e = t; e < KPAD * KPAD; e += 512) { W2s[e] = W2sub[e]; W3s[e] = W3sub[e]; }
  for (int e = t; e < DIM; e += 512) cms[e] = cmap[e];
  for (int e = t; e < 2 * 16 * KPAD; e += 512) ((float*)xs)[e] = 0.f;
  __syncthreads();

  const int  j   = t & 127;
  const int  rg  = (t >> 7) & 3;
  const bool jok = j < KACT;

  auto LOADR = [&](int ch, u16x8* ld) {
    const size_t base = (size_t)(row0 + ch * 16) * DIM;
    #pragma unroll
    for (int it = 0; it < 4; ++it) {
      int e = t + it * 512;
      int r = e >> 7, c8 = e & 127;
      ld[it] = *(const u16x8*)(xb + base + (size_t)r * DIM + c8 * 8);
    }
  };
  auto XSW = [&](int buf, const u16x8* ld) {
    #pragma unroll
    for (int it = 0; it < 4; ++it) {
      int e = t + it * 512;
      int r = e >> 7, c8 = e & 127;
      #pragma unroll
      for (int q = 0; q < 8; ++q) {
        int m = cms[c8 * 8 + q];
        if (m >= 0) xs[buf][r * KPAD + m] = bfasf(((unsigned)(unsigned short)ld[it][q]) << 16);
      }
    }
  };
  auto COMPUTE = [&](int buf) {
    if (jok) {
      float a2[4], a3[4];
      #pragma unroll
      for (int r = 0; r < 4; ++r) { a2[r] = 0.f; a3[r] = 0.f; }
      for (int i = 0; i < KPAD; i += 4) {
        float w2v[4], w3v[4];
        #pragma unroll
        for (int q = 0; q < 4; ++q) {
          w2v[q] = W2s[(i + q) * KPAD + j];
          w3v[q] = W3s[(i + q) * KPAD + j];
        }
        #pragma unroll
        for (int r = 0; r < 4; ++r) {
          f32x4 xv = *(const f32x4*)(&xs[buf][(rg * 4 + r) * KPAD + i]);
          a2[r] += xv[0] * w2v[0] + xv[1] * w2v[1] + xv[2] * w2v[2] + xv[3] * w2v[3];
          a3[r] += xv[0] * w3v[0] + xv[1] * w3v[1] + xv[2] * w3v[2] + xv[3] * w3v[3];
        }
      }
      #pragma unroll
      for (int r = 0; r < 4; ++r) {
        int rr = rg * 4 + r;
        float g = xs[buf][rr * KPAD + j];
        r2s[rr * KPAD + j] = a2[r] * g;
        r3s[rr * KPAD + j] = a3[r] * a3[r] * g;
      }
    }
  };
  auto WRITEOUT = [&](int ch) {
    const int r0 = row0 + ch * 16;
    const int c0 = (t & 255) * 4;
    const int rh = t >> 8;
    const int4 cm = *(const int4*)(&cms[c0]);
    #pragma unroll
    for (int k = 0; k < 8; ++k) {
      int r = rh + k * 2;
      const float* rr2 = &r2s[r * KPAD];
      const float* rr3 = &r3s[r * KPAD];
      float4 o2, o3;
      o2.x = (cm.x >= 0) ? rr2[cm.x] : 0.f;  o3.x = (cm.x >= 0) ? rr3[cm.x] : 0.f;
      o2.y = (cm.y >= 0) ? rr2[cm.y] : 0.f;  o3.y = (cm.y >= 0) ? rr3[cm.y] : 0.f;
      o2.z = (cm.z >= 0) ? rr2[cm.z] : 0.f;  o3.z = (cm.z >= 0) ? rr3[cm.z] : 0.f;
      o2.w = (cm.w >= 0) ? rr2[cm.w] : 0.f;  o3.w = (cm.w >= 0) ? rr3[cm.w] : 0.f;
      size_t oo = (size_t)(r0 + r) * DIM + c0;
      *(float4*)(out2 + oo) = o2;
      *(float4*)(out3 + oo) = o3;
    }
  };

  u16x8 ldA[4], ldB[4];
  LOADR(0, ldA);
  XSW(0, ldA);
  __syncthreads();
  for (int ch2 = 0; ch2 < 8; ch2 += 2) {
    if (ch2 + 1 < 8) LOADR(ch2 + 1, ldB);
    COMPUTE(0);
    __syncthreads();
    WRITEOUT(ch2);
    if (ch2 + 1 < 8) XSW(1, ldB);
    __syncthreads();
    if (ch2 + 2 < 8) LOADR(ch2 + 2, ldA);
    COMPUTE(1);
    __syncthreads();
    WRITEOUT(ch2 + 1);
    if (ch2 + 2 < 8) XSW(0, ldA);
    __syncthreads();
  }
}

// ---------------------------------------------------------------------------
extern "C" void kernel_launch(void* const* d_in, const int* in_sizes, int n_in,
                              void* d_out, int out_size, void* d_ws, size_t ws_size,
                              hipStream_t stream) {
  const float* x  = (const float*)d_in[0];
  const float* w1 = (const float*)d_in[1];
  const float* w2 = (const float*)d_in[2];
  const float* w3 = (const float*)d_in[3];

  float* out1 = (float*)d_out;
  float* out2 = out1 + (size_t)B_ROWS * DIM;
  float* out3 = out2 + (size_t)B_ROWS * DIM;

  char* ws = (char*)d_ws;
  unsigned short* xb     = (unsigned short*)ws;                  // 67108864 B
  unsigned short* w1t    = (unsigned short*)(ws + 67108864);     //  2097152 B
  float*          partial= (float*)(ws + 69206016);              //  2097152 B
  float*          p2     = (float*)(ws + 71303168);              //    32768 B
  int*            cmap   = (int*)(ws + 71335936);                //     4096 B
  int*            act    = (int*)(ws + 71340032);                //      512 B
  float*          W2sub  = (float*)(ws + 71340544);              //    43264 B
  float*          W3sub  = (float*)(ws + 71383808);              //    43264 B

  k_convw   <<<dim3(768),  dim3(256),  0, stream>>>(x, w1, xb, w1t, partial);
  k_reduce1 <<<dim3(64),   dim3(128),  0, stream>>>(partial, p2);
  k_sel     <<<dim3(1),    dim3(1024), 0, stream>>>(p2, act, cmap);
  k_wsub    <<<dim3(KPAD), dim3(128),  0, stream>>>(w2, w3, act, W2sub, W3sub);
  k_gemm_r1 <<<dim3(512),  dim3(512),  0, stream>>>(xb, w1t, out1);
  k_r23     <<<dim3(256),  dim3(512),  0, stream>>>(xb, W2sub, W3sub, cmap, out2, out3);
}

// Round 16
// 251.329 us; speedup vs baseline: 1.1721x; 1.0262x over previous
//
#include <hip/hip_runtime.h>
#include <hip/hip_bf16.h>
#include <stdint.h>

#define B_ROWS 32768
#define DIM    1024
#define KACT   102       // int(1024*0.1)
#define KPAD   104

typedef short bf16x8 __attribute__((ext_vector_type(8)));
typedef unsigned short u16x8 __attribute__((ext_vector_type(8)));
typedef float f32x4  __attribute__((ext_vector_type(4)));

__device__ __forceinline__ unsigned short f2bf(float f) {
  union { float f; unsigned u; } v; v.f = f;
  unsigned u = v.u;
  unsigned r = u + 0x7fffu + ((u >> 16) & 1u);   // RNE
  return (unsigned short)(r >> 16);
}
__device__ __forceinline__ float bfasf(unsigned hi16) {   // f32 from top-16 bits
  union { unsigned u; float f; } v; v.u = hi16;
  return v.f;
}

// async global->LDS, 16B per lane
#define GLDS(g, l) __builtin_amdgcn_global_load_lds( \
    (__attribute__((address_space(1))) void*)(g),    \
    (__attribute__((address_space(3))) void*)(l), 16, 0, 0)

// ---------------------------------------------------------------------------
// K1: merged conv + w1t (R10 verbatim).
// ---------------------------------------------------------------------------
__global__ __launch_bounds__(256) void k_convw(
    const float* __restrict__ x, const float* __restrict__ w1,
    unsigned short* __restrict__ xb, unsigned short* __restrict__ w1t,
    float* __restrict__ partial) {
  const int t = threadIdx.x;
  if (blockIdx.x < 512) {
    const int c0 = t * 4;
    const size_t base = (size_t)blockIdx.x * 64 * DIM;
    float s0 = 0.f, s1 = 0.f, s2 = 0.f, s3 = 0.f;
    #pragma unroll 4
    for (int j = 0; j < 64; ++j) {
      size_t off = base + (size_t)j * DIM + c0;
      float4 v = *(const float4*)(x + off);
      s0 += fabsf(v.x); s1 += fabsf(v.y); s2 += fabsf(v.z); s3 += fabsf(v.w);
      ushort4 o;
      o.x = f2bf(v.x); o.y = f2bf(v.y); o.z = f2bf(v.z); o.w = f2bf(v.w);
      *(ushort4*)(xb + off) = o;
    }
    float4 p; p.x = s0; p.y = s1; p.z = s2; p.w = s3;
    *(float4*)(partial + (size_t)blockIdx.x * DIM + c0) = p;
  } else {
    __shared__ unsigned short tile[64][65];
    const int b  = blockIdx.x - 512;
    const int bx = b & 15;
    const int by = b >> 4;
    for (int e = t; e < 64 * 64; e += 256) {
      int r = e >> 6, c = e & 63;
      tile[r][c] = f2bf(w1[(size_t)(by * 64 + r) * DIM + bx * 64 + c]);
    }
    __syncthreads();
    for (int e = t; e < 64 * 64; e += 256) {
      int c = e >> 6, r = e & 63;
      w1t[(size_t)(bx * 64 + c) * DIM + by * 64 + r] = tile[r][c];
    }
  }
}

// ---------------------------------------------------------------------------
// K2: reduce 512 partials -> 8 k-slice partials (R10 verbatim).
// ---------------------------------------------------------------------------
__global__ __launch_bounds__(128) void k_reduce1(const float* __restrict__ partial,
                                                 float* __restrict__ p2) {
  const int c  = (blockIdx.x & 7) * 128 + threadIdx.x;
  const int ks = blockIdx.x >> 3;
  float s = 0.f;
  #pragma unroll 8
  for (int p = ks * 64; p < ks * 64 + 64; ++p) s += partial[(size_t)p * DIM + c];
  p2[ks * DIM + c] = s;
}

// ---------------------------------------------------------------------------
// K3: rank + compact (R10 verbatim).
// ---------------------------------------------------------------------------
__global__ __launch_bounds__(1024) void k_sel(const float* __restrict__ p2,
                                              int* __restrict__ act,
                                              int* __restrict__ cmap) {
  __shared__ double sv[DIM];
  __shared__ int wcnt[16];
  const int d = threadIdx.x;
  {
    double s = 0.0;
    #pragma unroll
    for (int ks = 0; ks < 8; ++ks) s += (double)p2[ks * DIM + d];
    sv[d] = s;
  }
  __syncthreads();
  const double sd = sv[d];
  int rank = 0;
  for (int j = 0; j < DIM; ++j) {
    double s = sv[j];
    rank += (s > sd || (s == sd && j < d)) ? 1 : 0;
  }
  const int f = (rank < KACT) ? 1 : 0;
  unsigned long long m = __ballot(f != 0);
  const int lane = d & 63, w = d >> 6;
  if (lane == 0) wcnt[w] = __popcll(m);
  __syncthreads();
  int off = 0;
  for (int i = 0; i < w; ++i) off += wcnt[i];
  int pos = off + __popcll(m & ((1ull << lane) - 1ull));
  cmap[d] = f ? pos : -1;
  if (f) act[pos] = d;
}

// ---------------------------------------------------------------------------
// K4: gather compact W2sub/W3sub (R10 verbatim).
// ---------------------------------------------------------------------------
__global__ __launch_bounds__(128) void k_wsub(const float* __restrict__ w2,
                                              const float* __restrict__ w3,
                                              const int* __restrict__ act,
                                              float* __restrict__ W2sub,
                                              float* __restrict__ W3sub) {
  const int i = blockIdx.x;
  const int j = threadIdx.x;
  if (j >= KPAD) return;
  float v2 = 0.f, v3 = 0.f;
  if (i < KACT && j < KACT) {
    size_t o = (size_t)act[i] * DIM + act[j];
    v2 = w2[o]; v3 = w3[o];
  }
  W2sub[i * KPAD + j] = v2;
  W3sub[i * KPAD + j] = v3;
}

// ---------------------------------------------------------------------------
// K5: r1 = x @ w1 bf16 MFMA — R10 VERBATIM (best measured: 254.3 us total).
// 256x256 tile, 8 waves, BK=32, 4-slot ring, 2 phases/K-tile, depth-3
// prefetch (stage kt+3, vmcnt(8)), setprio, XOR bank swizzle.
// ---------------------------------------------------------------------------
#define VMW8 asm volatile("s_waitcnt vmcnt(8)" ::: "memory")
#define VMW4 asm volatile("s_waitcnt vmcnt(4)" ::: "memory")
#define VMW0 asm volatile("s_waitcnt vmcnt(0)" ::: "memory")
#define NOP_ (void)0

#define STAGE_A(KT) do { \
  GLDS(Abase + (size_t)sr0 * 1024 + (KT) * 32 + sc0 * 8, &Asl[((KT)&3)*8192 + p0*8]); \
  GLDS(Abase + (size_t)sr1 * 1024 + (KT) * 32 + sc1 * 8, &Asl[((KT)&3)*8192 + p1*8]); \
} while (0)
#define STAGE_B(KT) do { \
  GLDS(Bbase + (size_t)sr0 * 1024 + (KT) * 32 + sc0 * 8, &Bsl[((KT)&3)*8192 + p0*8]); \
  GLDS(Bbase + (size_t)sr1 * 1024 + (KT) * 32 + sc1 * 8, &Bsl[((KT)&3)*8192 + p1*8]); \
} while (0)

#define PH0(SLOT, STAGE_STMT) do { \
  _Pragma("unroll") for (int i = 0; i < 4; ++i) \
    areg[i] = *(const bf16x8*)(&Asl[(SLOT)*8192 + aoff0 + i * 512]); \
  _Pragma("unroll") for (int i = 0; i < 4; ++i) \
    breg[i] = *(const bf16x8*)(&Bsl[(SLOT)*8192 + boff0 + i * 512]); \
  STAGE_STMT; \
  __builtin_amdgcn_s_barrier(); \
  __builtin_amdgcn_s_setprio(1); \
  _Pragma("unroll") for (int mi = 0; mi < 4; ++mi) \
  _Pragma("unroll") for (int ni = 0; ni < 4; ++ni) \
    acc[mi][ni] = __builtin_amdgcn_mfma_f32_16x16x32_bf16(areg[mi], breg[ni], acc[mi][ni], 0, 0, 0); \
  __builtin_amdgcn_s_setprio(0); \
  __builtin_amdgcn_s_barrier(); \
} while (0)

#define PH1(SLOT, STAGE_STMT, WAIT_STMT) do { \
  _Pragma("unroll") for (int i = 0; i < 4; ++i) \
    areg[i] = *(const bf16x8*)(&Asl[(SLOT)*8192 + aoff0 + 2048 + i * 512]); \
  STAGE_STMT; \
  WAIT_STMT; \
  __builtin_amdgcn_s_barrier(); \
  __builtin_amdgcn_s_setprio(1); \
  _Pragma("unroll") for (int mi = 0; mi < 4; ++mi) \
  _Pragma("unroll") for (int ni = 0; ni < 4; ++ni) \
    acc[4 + mi][ni] = __builtin_amdgcn_mfma_f32_16x16x32_bf16(areg[mi], breg[ni], acc[4 + mi][ni], 0, 0, 0); \
  __builtin_amdgcn_s_setprio(0); \
  __builtin_amdgcn_s_barrier(); \
} while (0)

__global__ __launch_bounds__(512, 1) void k_gemm_r1(
    const unsigned short* __restrict__ A,
    const unsigned short* __restrict__ Bt,
    float* __restrict__ C) {
  __shared__ unsigned short Asl[4 * 8192];
  __shared__ unsigned short Bsl[4 * 8192];

  const int t    = threadIdx.x;
  const int lane = t & 63;
  const int wave = t >> 6;
  const int wm   = wave >> 2;
  const int wn   = wave & 3;
  const int la   = lane & 15;
  const int kg   = lane >> 4;
  const int kgx  = kg ^ ((la >> 1) & 3);

  const int swz  = (blockIdx.x & 7) * 64 + (blockIdx.x >> 3);
  const int brow = swz >> 2;
  const int bcol = swz & 3;

  const unsigned short* Abase = A  + (size_t)brow * 256 * 1024;
  const unsigned short* Bbase = Bt + (size_t)bcol * 256 * 1024;

  const int p0 = t, p1 = t + 512;
  const int q0 = p0 ^ ((p0 >> 3) & 3);
  const int q1 = p1 ^ ((p1 >> 3) & 3);
  const int sr0 = q0 >> 2, sc0 = q0 & 3;
  const int sr1 = q1 >> 2, sc1 = q1 & 3;

  const int aoff0 = (wm * 128 + la) * 32 + kgx * 8;
  const int boff0 = (wn * 64  + la) * 32 + kgx * 8;

  f32x4 acc[8][4];
  #pragma unroll
  for (int mi = 0; mi < 8; ++mi)
    #pragma unroll
    for (int ni = 0; ni < 4; ++ni)
      acc[mi][ni] = (f32x4){0.f, 0.f, 0.f, 0.f};

  bf16x8 areg[4], breg[4];

  // prologue: stage tiles 0,1,2 (12 loads); wait for tile 0 (8 in flight)
  STAGE_A(0); STAGE_B(0); STAGE_A(1); STAGE_B(1); STAGE_A(2); STAGE_B(2);
  VMW8;
  __builtin_amdgcn_s_barrier();

  // steady: compute kt, stage kt+3, vmcnt(8) -> tile kt+1 landed
  for (int kt4 = 0; kt4 < 28; kt4 += 4) {
    PH0(0, STAGE_A(kt4 + 3)); PH1(0, STAGE_B(kt4 + 3), VMW8);
    PH0(1, STAGE_A(kt4 + 4)); PH1(1, STAGE_B(kt4 + 4), VMW8);
    PH0(2, STAGE_A(kt4 + 5)); PH1(2, STAGE_B(kt4 + 5), VMW8);
    PH0(3, STAGE_A(kt4 + 6)); PH1(3, STAGE_B(kt4 + 6), VMW8);
  }
  PH0(0, STAGE_A(31)); PH1(0, STAGE_B(31), VMW8);   // kt=28 (last stage)
  PH0(1, NOP_);        PH1(1, NOP_, VMW4);          // kt=29 (tile 30 landed)
  PH0(2, NOP_);        PH1(2, NOP_, VMW0);          // kt=30 (tile 31 landed)
  PH0(3, NOP_);        PH1(3, NOP_, NOP_);          // kt=31

  const int orow0 = brow * 256 + wm * 128 + (lane >> 4) * 4;
  const int ocol0 = bcol * 256 + wn * 64 + la;
  #pragma unroll
  for (int mi = 0; mi < 8; ++mi)
    #pragma unroll
    for (int ni = 0; ni < 4; ++ni)
      #pragma unroll
      for (int r = 0; r < 4; ++r)
        C[(size_t)(orow0 + mi * 16 + r) * DIM + ocol0 + ni * 16] = acc[mi][ni][r];
}

// ---------------------------------------------------------------------------
// K6: r2/r3 — R10 verbatim.
// ---------------------------------------------------------------------------
__global__ __launch_bounds__(512) void k_r23(
    const unsigned short* __restrict__ xb,
    const float* __restrict__ W2sub,
    const float* __restrict__ W3sub,
    const int* __restrict__ cmap,
    float* __restrict__ out2,
    float* __restrict__ out3) {
  __shared__ float W2s[KPAD * KPAD];
  __shared__ float W3s[KPAD * KPAD];
  __shared__ float xs[2][16 * KPAD];
  __shared__ float r2s[16 * KPAD];
  __shared__ float r3s[16 * KPAD];
  __shared__ int   cms[DIM];
  const int t    = threadIdx.x;
  const int row0 = blockIdx.x * 128;

  for (int e = t; e < KPAD * KPAD; e += 512) { W2s[e] = W2sub[e]; W3s[e] = W3sub[e]; }
  for (int e = t; e < DIM; e += 512) cms[e] = cmap[e];
  for (int e = t; e < 2 * 16 * KPAD; e += 512) ((float*)xs)[e] = 0.f;
  __syncthreads();

  const int  j   = t & 127;
  const int  rg  = (t >> 7) & 3;
  const bool jok = j < KACT;

  auto LOADR = [&](int ch, u16x8* ld) {
    const size_t base = (size_t)(row0 + ch * 16) * DIM;
    #pragma unroll
    for (int it = 0; it < 4; ++it) {
      int e = t + it * 512;
      int r = e >> 7, c8 = e & 127;
      ld[it] = *(const u16x8*)(xb + base + (size_t)r * DIM + c8 * 8);
    }
  };
  auto XSW = [&](int buf, const u16x8* ld) {
    #pragma unroll
    for (int it = 0; it < 4; ++it) {
      int e = t + it * 512;
      int r = e >> 7, c8 = e & 127;
      #pragma unroll
      for (int q = 0; q < 8; ++q) {
        int m = cms[c8 * 8 + q];
        if (m >= 0) xs[buf][r * KPAD + m] = bfasf(((unsigned)(unsigned short)ld[it][q]) << 16);
      }
    }
  };
  auto COMPUTE = [&](int buf) {
    if (jok) {
      float a2[4], a3[4];
      #pragma unroll
      for (int r = 0; r < 4; ++r) { a2[r] = 0.f; a3[r] = 0.f; }
      for (int i = 0; i < KPAD; i += 4) {
        float w2v[4], w3v[4];
        #pragma unroll
        for (int q = 0; q < 4; ++q) {
          w2v[q] = W2s[(i + q) * KPAD + j];
          w3v[q] = W3s[(i + q) * KPAD + j];
        }
        #pragma unroll
        for (int r = 0; r < 4; ++r) {
          f32x4 xv = *(const f32x4*)(&xs[buf][(rg * 4 + r) * KPAD + i]);
          a2[r] += xv[0] * w2v[0] + xv[1] * w2v[1] + xv[2] * w2v[2] + xv[3] * w2v[3];
          a3[r] += xv[0] * w3v[0] + xv[1] * w3v[1] + xv[2] * w3v[2] + xv[3] * w3v[3];
        }
      }
      #pragma unroll
      for (int r = 0; r < 4; ++r) {
        int rr = rg * 4 + r;
        float g = xs[buf][rr * KPAD + j];
        r2s[rr * KPAD + j] = a2[r] * g;
        r3s[rr * KPAD + j] = a3[r] * a3[r] * g;
      }
    }
  };
  auto WRITEOUT = [&](int ch) {
    const int r0 = row0 + ch * 16;
    const int c0 = (t & 255) * 4;
    const int rh = t >> 8;
    const int4 cm = *(const int4*)(&cms[c0]);
    #pragma unroll
    for (int k = 0; k < 8; ++k) {
      int r = rh + k * 2;
      const float* rr2 = &r2s[r * KPAD];
      const float* rr3 = &r3s[r * KPAD];
      float4 o2, o3;
      o2.x = (cm.x >= 0) ? rr2[cm.x] : 0.f;  o3.x = (cm.x >= 0) ? rr3[cm.x] : 0.f;
      o2.y = (cm.y >= 0) ? rr2[cm.y] : 0.f;  o3.y = (cm.y >= 0) ? rr3[cm.y] : 0.f;
      o2.z = (cm.z >= 0) ? rr2[cm.z] : 0.f;  o3.z = (cm.z >= 0) ? rr3[cm.z] : 0.f;
      o2.w = (cm.w >= 0) ? rr2[cm.w] : 0.f;  o3.w = (cm.w >= 0) ? rr3[cm.w] : 0.f;
      size_t oo = (size_t)(r0 + r) * DIM + c0;
      *(float4*)(out2 + oo) = o2;
      *(float4*)(out3 + oo) = o3;
    }
  };

  u16x8 ldA[4], ldB[4];
  LOADR(0, ldA);
  XSW(0, ldA);
  __syncthreads();
  for (int ch2 = 0; ch2 < 8; ch2 += 2) {
    if (ch2 + 1 < 8) LOADR(ch2 + 1, ldB);
    COMPUTE(0);
    __syncthreads();
    WRITEOUT(ch2);
    if (ch2 + 1 < 8) XSW(1, ldB);
    __syncthreads();
    if (ch2 + 2 < 8) LOADR(ch2 + 2, ldA);
    COMPUTE(1);
    __syncthreads();
    WRITEOUT(ch2 + 1);
    if (ch2 + 2 < 8) XSW(0, ldA);
    __syncthreads();
  }
}

// ---------------------------------------------------------------------------
extern "C" void kernel_launch(void* const* d_in, const int* in_sizes, int n_in,
                              void* d_out, int out_size, void* d_ws, size_t ws_size,
                              hipStream_t stream) {
  const float* x  = (const float*)d_in[0];
  const float* w1 = (const float*)d_in[1];
  const float* w2 = (const float*)d_in[2];
  const float* w3 = (const float*)d_in[3];

  float* out1 = (float*)d_out;
  float* out2 = out1 + (size_t)B_ROWS * DIM;
  float* out3 = out2 + (size_t)B_ROWS * DIM;

  char* ws = (char*)d_ws;
  unsigned short* xb     = (unsigned short*)ws;                  // 67108864 B
  unsigned short* w1t    = (unsigned short*)(ws + 67108864);     //  2097152 B
  float*          partial= (float*)(ws + 69206016);              //  2097152 B
  float*          p2     = (float*)(ws + 71303168);              //    32768 B
  int*            cmap   = (int*)(ws + 71335936);                //     4096 B
  int*            act    = (int*)(ws + 71340032);                //      512 B
  float*          W2sub  = (float*)(ws + 71340544);              //    43264 B
  float*          W3sub  = (float*)(ws + 71383808);              //    43264 B

  k_convw   <<<dim3(768),  dim3(256),  0, stream>>>(x, w1, xb, w1t, partial);
  k_reduce1 <<<dim3(64),   dim3(128),  0, stream>>>(partial, p2);
  k_sel     <<<dim3(1),    dim3(1024), 0, stream>>>(p2, act, cmap);
  k_wsub    <<<dim3(KPAD), dim3(128),  0, stream>>>(w2, w3, act, W2sub, W3sub);
  k_gemm_r1 <<<dim3(512),  dim3(512),  0, stream>>>(xb, w1t, out1);
  k_r23     <<<dim3(256),  dim3(512),  0, stream>>>(xb, W2sub, W3sub, cmap, out2, out3);
}